// Round 1
// baseline (204.850 us; speedup 1.0000x reference)
//
#include <hip/hip_runtime.h>
#include <hip/hip_bf16.h>

#define LEAK 0.2f

typedef __attribute__((ext_vector_type(8))) short short8;
typedef __attribute__((ext_vector_type(4))) float f32x4;

// ---------- fp32 -> bf16 elementwise convert (4 elems/thread) ----------
__global__ __launch_bounds__(256) void k_convert(const float* __restrict__ x,
                                                 __hip_bfloat16* __restrict__ xb, int n4) {
  int idx = blockIdx.x * 256 + threadIdx.x;
  if (idx >= n4) return;
  float4 v = reinterpret_cast<const float4*>(x)[idx];
  union { ushort4 u; __hip_bfloat16 h[4]; } c;
  c.h[0] = __float2bfloat16(v.x);
  c.h[1] = __float2bfloat16(v.y);
  c.h[2] = __float2bfloat16(v.z);
  c.h[3] = __float2bfloat16(v.w);
  reinterpret_cast<ushort4*>(xb)[idx] = c.u;
}

// ---------- transpose + convert: W[K][N] fp32 -> Wt[Npad][K] bf16 (zero-pad n>=N) ----------
__global__ __launch_bounds__(256) void k_transpose(const float* __restrict__ W,
                                                   __hip_bfloat16* __restrict__ Wt,
                                                   int K, int N) {
  __shared__ float tile[32][33];
  int k0 = blockIdx.x * 32, n0 = blockIdx.y * 32;
  int tx = threadIdx.x, ty = threadIdx.y;  // blockDim = (32, 8)
#pragma unroll
  for (int r = 0; r < 4; ++r) {
    int k = k0 + ty + r * 8;
    int n = n0 + tx;
    tile[ty + r * 8][tx] = (n < N) ? W[(long)k * N + n] : 0.f;
  }
  __syncthreads();
#pragma unroll
  for (int r = 0; r < 4; ++r) {
    int n = n0 + ty + r * 8;
    int k = k0 + tx;
    Wt[(long)n * K + k] = __float2bfloat16(tile[tx][ty + r * 8]);
  }
}

// ---------- bf16 MFMA GEMM: C = act(A @ Bt^T + bias) ----------
// A[M][K] bf16 row-major, Bt[N][K] bf16 row-major. Block tile 64x64, BK=32,
// 4 waves in 2x2, each wave 32x32 = 2x2 MFMA tiles of 16x16x32.
template <bool RELU, bool HASB, bool OUTF, bool OUTB, bool TRANSF>
__global__ __launch_bounds__(256) void k_gemm(const __hip_bfloat16* __restrict__ A,
                                              const __hip_bfloat16* __restrict__ Bt,
                                              const float* __restrict__ bias,
                                              float* __restrict__ Cf,
                                              __hip_bfloat16* __restrict__ Cb,
                                              int M, int N, int K, int ldf) {
  __shared__ __align__(16) __hip_bfloat16 As[64][40];  // +8 pad: (row*5+quad)%8 distinct
  __shared__ __align__(16) __hip_bfloat16 Bs[64][40];
  int tid = threadIdx.x;
  int lane = tid & 63;
  int wv = tid >> 6;
  int wm = wv & 1, wn = wv >> 1;
  int quad = lane >> 4, l16 = lane & 15;
  long m0 = (long)blockIdx.x * 64, n0 = (long)blockIdx.y * 64;
  int srow = tid >> 2, scol = (tid & 3) * 8;
  const __hip_bfloat16* Ag = A + (m0 + srow) * K + scol;
  const __hip_bfloat16* Bg = Bt + (n0 + srow) * K + scol;

  f32x4 acc[2][2] = {};
  for (int kb = 0; kb < K; kb += 32) {
    *reinterpret_cast<int4*>(&As[srow][scol]) = *reinterpret_cast<const int4*>(Ag + kb);
    *reinterpret_cast<int4*>(&Bs[srow][scol]) = *reinterpret_cast<const int4*>(Bg + kb);
    __syncthreads();
    short8 af[2], bfr[2];
#pragma unroll
    for (int t = 0; t < 2; ++t) {
      af[t]  = *reinterpret_cast<const short8*>(&As[wm * 32 + t * 16 + l16][quad * 8]);
      bfr[t] = *reinterpret_cast<const short8*>(&Bs[wn * 32 + t * 16 + l16][quad * 8]);
    }
#pragma unroll
    for (int tm = 0; tm < 2; ++tm)
#pragma unroll
      for (int tn = 0; tn < 2; ++tn)
        acc[tm][tn] =
            __builtin_amdgcn_mfma_f32_16x16x32_bf16(af[tm], bfr[tn], acc[tm][tn], 0, 0, 0);
    __syncthreads();
  }

#pragma unroll
  for (int tm = 0; tm < 2; ++tm)
#pragma unroll
    for (int tn = 0; tn < 2; ++tn)
#pragma unroll
      for (int r = 0; r < 4; ++r) {
        long gm = m0 + wm * 32 + tm * 16 + quad * 4 + r;  // row = quad*4 + reg (m89/m91)
        long gn = n0 + wn * 32 + tn * 16 + l16;           // col = lane&15
        float v = acc[tm][tn][r];
        if (HASB) v += bias[gn];
        if (RELU) v = v > 0.f ? v : LEAK * v;
        if (OUTF) {
          if (TRANSF) Cf[gn * ldf + gm] = v;
          else        Cf[gm * ldf + gn] = v;
        }
        if (OUTB) Cb[gm * N + gn] = __float2bfloat16(v);
      }
}

// ---------- e^{+m}, e^{-m} precompute over mT[0:100][0:2048] ----------
__global__ __launch_bounds__(256) void k_exp(const float* __restrict__ mT,
                                             float* __restrict__ pT, float* __restrict__ nT) {
  int idx = blockIdx.x * 256 + threadIdx.x;  // < 100*2048
  float v = mT[idx];
  pT[idx] = __expf(v);
  nT[idx] = __expf(-v);
}

// ---------- pairwise: featsT[f][i] = sum_j min(e^{mi}e^{-mj}, e^{-mi}e^{mj}) ----------
__global__ __launch_bounds__(256) void k_pairwise(const float* __restrict__ pT,
                                                  const float* __restrict__ nT,
                                                  float* __restrict__ featsT) {
  __shared__ float Ps[2048];
  __shared__ float Ns[2048];
  int f = blockIdx.y;
  int tid = threadIdx.x;
  const float* prow = pT + (long)f * 2048;
  const float* nrow = nT + (long)f * 2048;
  for (int j = tid; j < 2048; j += 256) {
    Ps[j] = prow[j];
    Ns[j] = nrow[j];
  }
  __syncthreads();
  int ii = blockIdx.x * 256 + tid;
  float pi = Ps[ii], ni = Ns[ii];
  float a0 = 0.f, a1 = 0.f, a2 = 0.f, a3 = 0.f;
#pragma unroll 4
  for (int j = 0; j < 2048; j += 4) {
    float4 pj = *reinterpret_cast<const float4*>(&Ps[j]);
    float4 nj = *reinterpret_cast<const float4*>(&Ns[j]);
    a0 += fminf(pi * nj.x, ni * pj.x);
    a1 += fminf(pi * nj.y, ni * pj.y);
    a2 += fminf(pi * nj.z, ni * pj.z);
    a3 += fminf(pi * nj.w, ni * pj.w);
  }
  featsT[(long)f * 2048 + ii] = (a0 + a1) + (a2 + a3);
}

// ---------- final: out[i] = h2[i,:] . Wf[0:256] + featsT[:,i] . Wf[256:356] + bf ----------
__global__ __launch_bounds__(256) void k_final(const float* __restrict__ h2f,
                                               const float* __restrict__ featsT,
                                               const float* __restrict__ Wf,
                                               const float* __restrict__ bfp,
                                               float* __restrict__ out) {
  int wv = threadIdx.x >> 6, lane = threadIdx.x & 63;
  long i = (long)blockIdx.x * 4 + wv;
  const float* hrow = h2f + i * 256;
  float s = 0.f;
#pragma unroll
  for (int c = lane; c < 256; c += 64) s += hrow[c] * Wf[c];
  for (int f = lane; f < 100; f += 64) s += featsT[(long)f * 2048 + i] * Wf[256 + f];
#pragma unroll
  for (int off = 32; off; off >>= 1) s += __shfl_down(s, off);
  if (lane == 0) out[i] = s + bfp[0];
}

extern "C" void kernel_launch(void* const* d_in, const int* in_sizes, int n_in,
                              void* d_out, int out_size, void* d_ws, size_t ws_size,
                              hipStream_t stream) {
  const float* x  = (const float*)d_in[0];
  const float* W1 = (const float*)d_in[1];
  const float* b1 = (const float*)d_in[2];
  const float* W2 = (const float*)d_in[3];
  const float* b2 = (const float*)d_in[4];
  const float* T  = (const float*)d_in[5];
  const float* Wf = (const float*)d_in[6];
  const float* bf = (const float*)d_in[7];
  float* out = (float*)d_out;

  char* w = (char*)d_ws;
  auto alloc = [&](size_t b) { char* p = w; w += (b + 255) & ~(size_t)255; return p; };
  __hip_bfloat16* xb   = (__hip_bfloat16*)alloc(2048L * 3072 * 2);
  __hip_bfloat16* W1t  = (__hip_bfloat16*)alloc(512L * 3072 * 2);
  __hip_bfloat16* W2t  = (__hip_bfloat16*)alloc(256L * 512 * 2);
  __hip_bfloat16* Tt   = (__hip_bfloat16*)alloc(128L * 256 * 2);
  __hip_bfloat16* h1b  = (__hip_bfloat16*)alloc(2048L * 512 * 2);
  float*          h2f  = (float*)alloc(2048L * 256 * 4);
  __hip_bfloat16* h2b  = (__hip_bfloat16*)alloc(2048L * 256 * 2);
  float*          mT   = (float*)alloc(128L * 2048 * 4);
  float*          pT   = (float*)alloc(100L * 2048 * 4);
  float*          nT   = (float*)alloc(100L * 2048 * 4);
  float*          feT  = (float*)alloc(100L * 2048 * 4);

  // x -> bf16
  k_convert<<<6144, 256, 0, stream>>>(x, xb, 1572864);
  // W1 (3072x512) -> W1t (512x3072), W2 (512x256) -> W2t (256x512), T (256x100) -> Tt (128x256, zero-padded)
  k_transpose<<<dim3(96, 16), dim3(32, 8), 0, stream>>>(W1, W1t, 3072, 512);
  k_transpose<<<dim3(16, 8),  dim3(32, 8), 0, stream>>>(W2, W2t, 512, 256);
  k_transpose<<<dim3(8, 4),   dim3(32, 8), 0, stream>>>(T,  Tt,  256, 100);
  // h1 = leakyrelu(x @ W1 + b1)  -> bf16
  k_gemm<true, true, false, true, false><<<dim3(32, 8), 256, 0, stream>>>(
      xb, W1t, b1, nullptr, h1b, 2048, 512, 3072, 0);
  // h2 = leakyrelu(h1 @ W2 + b2) -> fp32 + bf16
  k_gemm<true, true, true, true, false><<<dim3(32, 4), 256, 0, stream>>>(
      h1b, W2t, b2, h2f, h2b, 2048, 256, 512, 256);
  // mT = (h2 @ T)^T  (transposed store, ld = 2048; cols >= 100 are zero via padded Tt)
  k_gemm<false, false, true, false, true><<<dim3(32, 2), 256, 0, stream>>>(
      h2b, Tt, nullptr, mT, nullptr, 2048, 128, 256, 2048);
  // e^{+-m}
  k_exp<<<800, 256, 0, stream>>>(mT, pT, nT);
  // feats
  k_pairwise<<<dim3(8, 100), 256, 0, stream>>>(pT, nT, feT);
  // final dot
  k_final<<<512, 256, 0, stream>>>(h2f, feT, Wf, bf, out);
}

// Round 2
// 175.036 us; speedup vs baseline: 1.1703x; 1.1703x over previous
//
#include <hip/hip_runtime.h>
#include <hip/hip_bf16.h>

#define LEAK 0.2f

typedef __attribute__((ext_vector_type(8))) short short8;
typedef __attribute__((ext_vector_type(4))) float f32x4;

// ---------- fp32 -> bf16 elementwise convert (4 elems/thread) ----------
__global__ __launch_bounds__(256) void k_convert(const float* __restrict__ x,
                                                 __hip_bfloat16* __restrict__ xb, int n4) {
  int idx = blockIdx.x * 256 + threadIdx.x;
  if (idx >= n4) return;
  float4 v = reinterpret_cast<const float4*>(x)[idx];
  union { ushort4 u; __hip_bfloat16 h[4]; } c;
  c.h[0] = __float2bfloat16(v.x);
  c.h[1] = __float2bfloat16(v.y);
  c.h[2] = __float2bfloat16(v.z);
  c.h[3] = __float2bfloat16(v.w);
  reinterpret_cast<ushort4*>(xb)[idx] = c.u;
}

// ---------- transpose + convert: W[K][N] fp32 -> Wt[Npad][K] bf16 (zero-pad n>=N) ----------
__global__ __launch_bounds__(256) void k_transpose(const float* __restrict__ W,
                                                   __hip_bfloat16* __restrict__ Wt,
                                                   int K, int N) {
  __shared__ float tile[32][33];
  int k0 = blockIdx.x * 32, n0 = blockIdx.y * 32;
  int tx = threadIdx.x, ty = threadIdx.y;  // blockDim = (32, 8)
#pragma unroll
  for (int r = 0; r < 4; ++r) {
    int k = k0 + ty + r * 8;
    int n = n0 + tx;
    tile[ty + r * 8][tx] = (n < N) ? W[(long)k * N + n] : 0.f;
  }
  __syncthreads();
#pragma unroll
  for (int r = 0; r < 4; ++r) {
    int n = n0 + ty + r * 8;
    int k = k0 + tx;
    Wt[(long)n * K + k] = __float2bfloat16(tile[tx][ty + r * 8]);
  }
}

// ---------- bf16 MFMA GEMM, split-K: Cp[z] = A[:, z*KSPL:(z+1)*KSPL] @ Bt^T ----------
// A[M][K] bf16 row-major, Bt[N][K] bf16 row-major. Block tile 64x64, BK=32,
// 4 waves in 2x2, each wave 32x32 = 2x2 MFMA tiles of 16x16x32.
// Register prefetch of the next global tile overlaps MFMA+ds_read.
__global__ __launch_bounds__(256) void k_gemm(const __hip_bfloat16* __restrict__ A,
                                              const __hip_bfloat16* __restrict__ Bt,
                                              float* __restrict__ Cp,
                                              int M, int N, int K, int KSPL) {
  __shared__ __align__(16) __hip_bfloat16 As[64][40];  // +8 pad
  __shared__ __align__(16) __hip_bfloat16 Bs[64][40];
  int tid = threadIdx.x;
  int lane = tid & 63;
  int wv = tid >> 6;
  int wm = wv & 1, wn = wv >> 1;
  int quad = lane >> 4, l16 = lane & 15;
  long m0 = (long)blockIdx.x * 64, n0 = (long)blockIdx.y * 64;
  int srow = tid >> 2, scol = (tid & 3) * 8;
  int kStart = blockIdx.z * KSPL;
  const __hip_bfloat16* Ag = A + (m0 + srow) * K + kStart + scol;
  const __hip_bfloat16* Bg = Bt + (n0 + srow) * K + kStart + scol;

  int4 ra = *reinterpret_cast<const int4*>(Ag);
  int4 rb = *reinterpret_cast<const int4*>(Bg);

  f32x4 acc[2][2] = {};
  for (int kb = 0; kb < KSPL; kb += 32) {
    *reinterpret_cast<int4*>(&As[srow][scol]) = ra;
    *reinterpret_cast<int4*>(&Bs[srow][scol]) = rb;
    __syncthreads();
    if (kb + 32 < KSPL) {
      ra = *reinterpret_cast<const int4*>(Ag + kb + 32);
      rb = *reinterpret_cast<const int4*>(Bg + kb + 32);
    }
    short8 af[2], bfr[2];
#pragma unroll
    for (int t = 0; t < 2; ++t) {
      af[t]  = *reinterpret_cast<const short8*>(&As[wm * 32 + t * 16 + l16][quad * 8]);
      bfr[t] = *reinterpret_cast<const short8*>(&Bs[wn * 32 + t * 16 + l16][quad * 8]);
    }
#pragma unroll
    for (int tm = 0; tm < 2; ++tm)
#pragma unroll
      for (int tn = 0; tn < 2; ++tn)
        acc[tm][tn] =
            __builtin_amdgcn_mfma_f32_16x16x32_bf16(af[tm], bfr[tn], acc[tm][tn], 0, 0, 0);
    __syncthreads();
  }

  float* Cz = Cp + (long)blockIdx.z * M * N;
#pragma unroll
  for (int tm = 0; tm < 2; ++tm)
#pragma unroll
    for (int tn = 0; tn < 2; ++tn)
#pragma unroll
      for (int r = 0; r < 4; ++r) {
        long gm = m0 + wm * 32 + tm * 16 + quad * 4 + r;  // row = quad*4 + reg
        long gn = n0 + wn * 32 + tn * 16 + l16;           // col = lane&15
        Cz[gm * N + gn] = acc[tm][tn][r];
      }
}

// ---------- combine 2 partials + bias + leakyrelu -> bf16 ----------
__global__ __launch_bounds__(256) void k_comb1(const float* __restrict__ P,
                                               const float* __restrict__ bias,
                                               __hip_bfloat16* __restrict__ Ob,
                                               int total4, int nmask) {
  int idx = blockIdx.x * 256 + threadIdx.x;
  if (idx >= total4) return;
  float4 a = reinterpret_cast<const float4*>(P)[idx];
  float4 b = reinterpret_cast<const float4*>(P + (long)total4 * 4)[idx];
  int col = (idx * 4) & nmask;
  float4 bs = *reinterpret_cast<const float4*>(bias + col);
  float v0 = a.x + b.x + bs.x, v1 = a.y + b.y + bs.y;
  float v2 = a.z + b.z + bs.z, v3 = a.w + b.w + bs.w;
  v0 = v0 > 0.f ? v0 : LEAK * v0;
  v1 = v1 > 0.f ? v1 : LEAK * v1;
  v2 = v2 > 0.f ? v2 : LEAK * v2;
  v3 = v3 > 0.f ? v3 : LEAK * v3;
  union { ushort4 u; __hip_bfloat16 h[4]; } c;
  c.h[0] = __float2bfloat16(v0);
  c.h[1] = __float2bfloat16(v1);
  c.h[2] = __float2bfloat16(v2);
  c.h[3] = __float2bfloat16(v3);
  reinterpret_cast<ushort4*>(Ob)[idx] = c.u;
}

// ---------- combine 2 partials + bias + leakyrelu -> fp32 AND bf16 ----------
__global__ __launch_bounds__(256) void k_comb2(const float* __restrict__ P,
                                               const float* __restrict__ bias,
                                               float* __restrict__ Of,
                                               __hip_bfloat16* __restrict__ Ob,
                                               int total4, int nmask) {
  int idx = blockIdx.x * 256 + threadIdx.x;
  if (idx >= total4) return;
  float4 a = reinterpret_cast<const float4*>(P)[idx];
  float4 b = reinterpret_cast<const float4*>(P + (long)total4 * 4)[idx];
  int col = (idx * 4) & nmask;
  float4 bs = *reinterpret_cast<const float4*>(bias + col);
  float4 v;
  v.x = a.x + b.x + bs.x;
  v.y = a.y + b.y + bs.y;
  v.z = a.z + b.z + bs.z;
  v.w = a.w + b.w + bs.w;
  v.x = v.x > 0.f ? v.x : LEAK * v.x;
  v.y = v.y > 0.f ? v.y : LEAK * v.y;
  v.z = v.z > 0.f ? v.z : LEAK * v.z;
  v.w = v.w > 0.f ? v.w : LEAK * v.w;
  reinterpret_cast<float4*>(Of)[idx] = v;
  union { ushort4 u; __hip_bfloat16 h[4]; } c;
  c.h[0] = __float2bfloat16(v.x);
  c.h[1] = __float2bfloat16(v.y);
  c.h[2] = __float2bfloat16(v.z);
  c.h[3] = __float2bfloat16(v.w);
  reinterpret_cast<ushort4*>(Ob)[idx] = c.u;
}

// ---------- sort-based minibatch-discrimination features, O(B log B) ----------
// For feature f: sort m-values; D[k]=sum_{j<=k} e^{v_j-v_k} and
// U[k]=sum_{j>=k} e^{v_k-v_j} via affine scans (all exp args <= 0, no overflow).
// feats[idx_k] = D[k] + U[k] - 1.
__global__ __launch_bounds__(1024) void k_sortfeats(const float* __restrict__ P4,
                                                    float* __restrict__ featsT) {
  __shared__ __align__(16) char smem[53248];                       // 52 KB
  unsigned long long* keys = (unsigned long long*)smem;            // [0,16K)
  float* sv = (float*)(smem + 16384);                              // [16K,24K)
  unsigned short* sidx = (unsigned short*)(smem + 24576);          // [24K,28K)
  float2* sA = (float2*)smem;                                      // alias keys
  float2* sB = (float2*)(smem + 28672);                            // [28K,44K)
  float* Dres = (float*)(smem + 45056);                            // [44K,52K)
  int f = blockIdx.x;
  int t = threadIdx.x;
  const long FS = 2048L * 128;

  // load column f (summing 4 split-K partials), pack order-preserving key|index
  for (int e = t; e < 2048; e += 1024) {
    float v = P4[(long)e * 128 + f] + P4[FS + (long)e * 128 + f] +
              P4[2 * FS + (long)e * 128 + f] + P4[3 * FS + (long)e * 128 + f];
    unsigned u = __float_as_uint(v);
    u = (u & 0x80000000u) ? ~u : (u | 0x80000000u);
    keys[e] = ((unsigned long long)u << 32) | (unsigned)e;
  }
  __syncthreads();

  // bitonic sort, ascending
  for (int k = 2; k <= 2048; k <<= 1)
    for (int j = k >> 1; j > 0; j >>= 1) {
#pragma unroll
      for (int eo = 0; eo < 2048; eo += 1024) {
        int e = t + eo;
        int l = e ^ j;
        if (l > e) {
          unsigned long long a = keys[e], b = keys[l];
          bool up = ((e & k) == 0);
          if ((a > b) == up) { keys[e] = b; keys[l] = a; }
        }
      }
      __syncthreads();
    }

  // unpack sorted values + original indices
  for (int e = t; e < 2048; e += 1024) {
    unsigned long long kk = keys[e];
    unsigned u = (unsigned)(kk >> 32);
    unsigned ub = (u & 0x80000000u) ? (u & 0x7FFFFFFFu) : ~u;
    sv[e] = __uint_as_float(ub);
    sidx[e] = (unsigned short)(kk & 0xFFFFu);
  }
  __syncthreads();  // keys dead; sA (alias) live from here

  // forward scan: D[k] = a_k*D[k-1] + 1, a_k = e^{v[k-1]-v[k]}
  for (int e = t; e < 2048; e += 1024) {
    float a = (e == 0) ? 0.f : __expf(sv[e - 1] - sv[e]);
    sA[e] = make_float2(a, 1.f);
  }
  __syncthreads();
  float2* cur = sA;
  float2* oth = sB;
  for (int off = 1; off < 2048; off <<= 1) {
    for (int e = t; e < 2048; e += 1024) {
      float2 x = cur[e];
      if (e >= off) {
        float2 y = cur[e - off];
        x = make_float2(x.x * y.x, x.x * y.y + x.y);  // compose left-then-right
      }
      oth[e] = x;
    }
    __syncthreads();
    float2* tmp = cur; cur = oth; oth = tmp;
  }
  // 11 rounds -> cur == sB. Save D, init reversed scan into sA (disjoint).
  for (int e = t; e < 2048; e += 1024) Dres[e] = cur[e].y;
  for (int e = t; e < 2048; e += 1024) {
    int p = 2047 - e;
    float a = (e == 2047) ? 0.f : __expf(sv[e] - sv[e + 1]);
    sA[p] = make_float2(a, 1.f);
  }
  __syncthreads();
  cur = sA; oth = sB;
  for (int off = 1; off < 2048; off <<= 1) {
    for (int e = t; e < 2048; e += 1024) {
      float2 x = cur[e];
      if (e >= off) {
        float2 y = cur[e - off];
        x = make_float2(x.x * y.x, x.x * y.y + x.y);
      }
      oth[e] = x;
    }
    __syncthreads();
    float2* tmp = cur; cur = oth; oth = tmp;
  }
  // U[k] = cur[2047-k].y
  for (int e = t; e < 2048; e += 1024) {
    float feat = Dres[e] + cur[2047 - e].y - 1.0f;
    featsT[(long)f * 2048 + sidx[e]] = feat;
  }
}

// ---------- final: out[i] = h2[i,:] . Wf[0:256] + featsT[:,i] . Wf[256:356] + bf ----------
__global__ __launch_bounds__(256) void k_final(const float* __restrict__ h2f,
                                               const float* __restrict__ featsT,
                                               const float* __restrict__ Wf,
                                               const float* __restrict__ bfp,
                                               float* __restrict__ out) {
  int wv = threadIdx.x >> 6, lane = threadIdx.x & 63;
  long i = (long)blockIdx.x * 4 + wv;
  const float* hrow = h2f + i * 256;
  float s = 0.f;
#pragma unroll
  for (int c = lane; c < 256; c += 64) s += hrow[c] * Wf[c];
  for (int f = lane; f < 100; f += 64) s += featsT[(long)f * 2048 + i] * Wf[256 + f];
#pragma unroll
  for (int off = 32; off; off >>= 1) s += __shfl_down(s, off);
  if (lane == 0) out[i] = s + bfp[0];
}

extern "C" void kernel_launch(void* const* d_in, const int* in_sizes, int n_in,
                              void* d_out, int out_size, void* d_ws, size_t ws_size,
                              hipStream_t stream) {
  const float* x  = (const float*)d_in[0];
  const float* W1 = (const float*)d_in[1];
  const float* b1 = (const float*)d_in[2];
  const float* W2 = (const float*)d_in[3];
  const float* b2 = (const float*)d_in[4];
  const float* T  = (const float*)d_in[5];
  const float* Wf = (const float*)d_in[6];
  const float* bf = (const float*)d_in[7];
  float* out = (float*)d_out;

  char* w = (char*)d_ws;
  auto alloc = [&](size_t b) { char* p = w; w += (b + 255) & ~(size_t)255; return p; };
  char*           xbr  = alloc(2048L * 3072 * 2);   // 12 MB, reused after G1
  __hip_bfloat16* xb   = (__hip_bfloat16*)xbr;
  float*          P2   = (float*)xbr;               // alias: live after xb dead
  float*          P3   = (float*)(xbr + 4194304);   // alias
  float*          feT  = (float*)(xbr + 8388608);   // alias
  __hip_bfloat16* W1t  = (__hip_bfloat16*)alloc(512L * 3072 * 2);
  __hip_bfloat16* W2t  = (__hip_bfloat16*)alloc(256L * 512 * 2);
  __hip_bfloat16* Tt   = (__hip_bfloat16*)alloc(128L * 256 * 2);
  __hip_bfloat16* h1b  = (__hip_bfloat16*)alloc(2048L * 512 * 2);
  float*          h2f  = (float*)alloc(2048L * 256 * 4);
  __hip_bfloat16* h2b  = (__hip_bfloat16*)alloc(2048L * 256 * 2);
  float*          P1   = (float*)alloc(2L * 2048 * 512 * 4);  // 8 MB

  // x -> bf16
  k_convert<<<6144, 256, 0, stream>>>(x, xb, 1572864);
  // weight transposes (bf16, zero-padded)
  k_transpose<<<dim3(96, 16), dim3(32, 8), 0, stream>>>(W1, W1t, 3072, 512);
  k_transpose<<<dim3(16, 8),  dim3(32, 8), 0, stream>>>(W2, W2t, 512, 256);
  k_transpose<<<dim3(8, 4),   dim3(32, 8), 0, stream>>>(T,  Tt,  256, 100);
  // h1 = leakyrelu(x @ W1 + b1): split-K=2
  k_gemm<<<dim3(32, 8, 2), 256, 0, stream>>>(xb, W1t, P1, 2048, 512, 3072, 1536);
  k_comb1<<<1024, 256, 0, stream>>>(P1, b1, h1b, 262144, 511);
  // h2 = leakyrelu(h1 @ W2 + b2): split-K=2
  k_gemm<<<dim3(32, 4, 2), 256, 0, stream>>>(h1b, W2t, P2, 2048, 256, 512, 256);
  k_comb2<<<512, 256, 0, stream>>>(P2, b2, h2f, h2b, 131072, 255);
  // m = h2 @ T: split-K=4, partials consumed directly by sort kernel
  k_gemm<<<dim3(32, 2, 4), 256, 0, stream>>>(h2b, Tt, P3, 2048, 128, 256, 64);
  // minibatch-discrimination features via per-feature sort + affine scans
  k_sortfeats<<<100, 1024, 0, stream>>>(P3, feT);
  // final dot
  k_final<<<512, 256, 0, stream>>>(h2f, feT, Wf, bf, out);
}

// Round 3
// 138.128 us; speedup vs baseline: 1.4830x; 1.2672x over previous
//
#include <hip/hip_runtime.h>
#include <hip/hip_bf16.h>

#define LEAK 0.2f

typedef __attribute__((ext_vector_type(8))) short short8;
typedef __attribute__((ext_vector_type(4))) float f32x4;

// ---------- fp32 -> bf16 elementwise convert (4 elems/thread) ----------
__global__ __launch_bounds__(256) void k_convert(const float* __restrict__ x,
                                                 __hip_bfloat16* __restrict__ xb, int n4) {
  int idx = blockIdx.x * 256 + threadIdx.x;
  if (idx >= n4) return;
  float4 v = reinterpret_cast<const float4*>(x)[idx];
  union { ushort4 u; __hip_bfloat16 h[4]; } c;
  c.h[0] = __float2bfloat16(v.x);
  c.h[1] = __float2bfloat16(v.y);
  c.h[2] = __float2bfloat16(v.z);
  c.h[3] = __float2bfloat16(v.w);
  reinterpret_cast<ushort4*>(xb)[idx] = c.u;
}

// ---------- transpose + convert: W[K][N] fp32 -> Wt[Npad][K] bf16 (zero-pad n>=N) ----------
__global__ __launch_bounds__(256) void k_transpose(const float* __restrict__ W,
                                                   __hip_bfloat16* __restrict__ Wt,
                                                   int K, int N) {
  __shared__ float tile[32][33];
  int k0 = blockIdx.x * 32, n0 = blockIdx.y * 32;
  int tx = threadIdx.x, ty = threadIdx.y;  // blockDim = (32, 8)
#pragma unroll
  for (int r = 0; r < 4; ++r) {
    int k = k0 + ty + r * 8;
    int n = n0 + tx;
    tile[ty + r * 8][tx] = (n < N) ? W[(long)k * N + n] : 0.f;
  }
  __syncthreads();
#pragma unroll
  for (int r = 0; r < 4; ++r) {
    int n = n0 + ty + r * 8;
    int k = k0 + tx;
    Wt[(long)n * K + k] = __float2bfloat16(tile[tx][ty + r * 8]);
  }
}

// ---------- bf16 MFMA GEMM, split-K: Cp[z] = A[:, z*KSPL:(z+1)*KSPL] @ Bt^T ----------
// A[M][K] bf16 row-major, Bt[N][K] bf16 row-major. Block tile 64x64, BK=32,
// 4 waves in 2x2, each wave 32x32 = 2x2 MFMA tiles of 16x16x32.
// TRANSP: store partial transposed (Cz[n][m], ld = ldO).
template <bool TRANSP>
__global__ __launch_bounds__(256) void k_gemm(const __hip_bfloat16* __restrict__ A,
                                              const __hip_bfloat16* __restrict__ Bt,
                                              float* __restrict__ Cp,
                                              int M, int N, int K, int KSPL, int ldO) {
  __shared__ __align__(16) __hip_bfloat16 As[64][40];  // +8 pad
  __shared__ __align__(16) __hip_bfloat16 Bs[64][40];
  int tid = threadIdx.x;
  int lane = tid & 63;
  int wv = tid >> 6;
  int wm = wv & 1, wn = wv >> 1;
  int quad = lane >> 4, l16 = lane & 15;
  long m0 = (long)blockIdx.x * 64, n0 = (long)blockIdx.y * 64;
  int srow = tid >> 2, scol = (tid & 3) * 8;
  int kStart = blockIdx.z * KSPL;
  const __hip_bfloat16* Ag = A + (m0 + srow) * K + kStart + scol;
  const __hip_bfloat16* Bg = Bt + (n0 + srow) * K + kStart + scol;

  int4 ra = *reinterpret_cast<const int4*>(Ag);
  int4 rb = *reinterpret_cast<const int4*>(Bg);

  f32x4 acc[2][2] = {};
  for (int kb = 0; kb < KSPL; kb += 32) {
    *reinterpret_cast<int4*>(&As[srow][scol]) = ra;
    *reinterpret_cast<int4*>(&Bs[srow][scol]) = rb;
    __syncthreads();
    if (kb + 32 < KSPL) {
      ra = *reinterpret_cast<const int4*>(Ag + kb + 32);
      rb = *reinterpret_cast<const int4*>(Bg + kb + 32);
    }
    short8 af[2], bfr[2];
#pragma unroll
    for (int t = 0; t < 2; ++t) {
      af[t]  = *reinterpret_cast<const short8*>(&As[wm * 32 + t * 16 + l16][quad * 8]);
      bfr[t] = *reinterpret_cast<const short8*>(&Bs[wn * 32 + t * 16 + l16][quad * 8]);
    }
#pragma unroll
    for (int tm = 0; tm < 2; ++tm)
#pragma unroll
      for (int tn = 0; tn < 2; ++tn)
        acc[tm][tn] =
            __builtin_amdgcn_mfma_f32_16x16x32_bf16(af[tm], bfr[tn], acc[tm][tn], 0, 0, 0);
    __syncthreads();
  }

  float* Cz = Cp + (long)blockIdx.z * M * N;
#pragma unroll
  for (int tm = 0; tm < 2; ++tm)
#pragma unroll
    for (int tn = 0; tn < 2; ++tn)
#pragma unroll
      for (int r = 0; r < 4; ++r) {
        long gm = m0 + wm * 32 + tm * 16 + quad * 4 + r;  // row = quad*4 + reg
        long gn = n0 + wn * 32 + tn * 16 + l16;           // col = lane&15
        if (TRANSP) Cz[gn * ldO + gm] = acc[tm][tn][r];
        else        Cz[gm * ldO + gn] = acc[tm][tn][r];
      }
}

// ---------- combine NZ partials + bias + leakyrelu -> bf16 (+ optional fp32) ----------
template <int NZ, bool OUTF>
__global__ __launch_bounds__(256) void k_comb(const float* __restrict__ P,
                                              const float* __restrict__ bias,
                                              float* __restrict__ Of,
                                              __hip_bfloat16* __restrict__ Ob,
                                              int total4, int nmask) {
  int idx = blockIdx.x * 256 + threadIdx.x;
  if (idx >= total4) return;
  float4 v = reinterpret_cast<const float4*>(P)[idx];
#pragma unroll
  for (int z = 1; z < NZ; ++z) {
    float4 a = reinterpret_cast<const float4*>(P + (long)z * total4 * 4)[idx];
    v.x += a.x; v.y += a.y; v.z += a.z; v.w += a.w;
  }
  int col = (idx * 4) & nmask;
  float4 bs = *reinterpret_cast<const float4*>(bias + col);
  v.x += bs.x; v.y += bs.y; v.z += bs.z; v.w += bs.w;
  v.x = v.x > 0.f ? v.x : LEAK * v.x;
  v.y = v.y > 0.f ? v.y : LEAK * v.y;
  v.z = v.z > 0.f ? v.z : LEAK * v.z;
  v.w = v.w > 0.f ? v.w : LEAK * v.w;
  if (OUTF) reinterpret_cast<float4*>(Of)[idx] = v;
  union { ushort4 u; __hip_bfloat16 h[4]; } c;
  c.h[0] = __float2bfloat16(v.x);
  c.h[1] = __float2bfloat16(v.y);
  c.h[2] = __float2bfloat16(v.z);
  c.h[3] = __float2bfloat16(v.w);
  reinterpret_cast<ushort4*>(Ob)[idx] = c.u;
}

// ---------- bucketed minibatch-discrimination features, O(B) ----------
// feats[i] = sum_j e^{-|mi-mj|}. Bucket by value (256 equal-width buckets):
// lower buckets contribute n_i * sum(p_j), upper buckets p_i * sum(n_j)
// (exact: bucket order is monotone in m), own bucket exact pairwise.
// p,n centered at mid=(min+max)/2, args clamped to +-60 (clamp error < e^-70).
// One block (1024 thr) per feature; mTz is 4 transposed split-K partials.
__global__ __launch_bounds__(1024) void k_bucketfeats(const float* __restrict__ mTz,
                                                      float* __restrict__ featsT) {
  __shared__ float sP[2048], sN[2048];     // unsorted p,n by element
  __shared__ float Sp[2048], Sn[2048];     // bucket-ordered p,n
  __shared__ int Smeta[2048];              // (bucket<<16)|orig_idx per slot
  __shared__ short sB[2048];               // bucket per element
  __shared__ int cnt[256], bstart[256], bcur[256];
  __shared__ float bsP[256], bsN[256], Pbel[256], Nab[256];
  __shared__ float wred[32];
  __shared__ float sMin, sMax;
  int f = blockIdx.x;
  int t = threadIdx.x;
  int lane = t & 63, wv = t >> 6;
  const long FS = 2048L * 128;
  const float* row = mTz + (long)f * 2048;

  float m[2];
  float lmin = 3.4e38f, lmax = -3.4e38f;
#pragma unroll
  for (int r = 0; r < 2; ++r) {
    int e = t + r * 1024;
    float v = row[e] + row[FS + e] + row[2 * FS + e] + row[3 * FS + e];
    m[r] = v;
    lmin = fminf(lmin, v);
    lmax = fmaxf(lmax, v);
  }
#pragma unroll
  for (int d = 32; d; d >>= 1) {
    lmin = fminf(lmin, __shfl_down(lmin, d));
    lmax = fmaxf(lmax, __shfl_down(lmax, d));
  }
  if (lane == 0) { wred[wv] = lmin; wred[16 + wv] = lmax; }
  if (t < 256) cnt[t] = 0;
  __syncthreads();
  if (t == 0) {
    float a = wred[0], b = wred[16];
    for (int i = 1; i < 16; ++i) { a = fminf(a, wred[i]); b = fmaxf(b, wred[16 + i]); }
    sMin = a; sMax = b;
  }
  __syncthreads();
  float mn = sMin, mx = sMax;
  float rge = mx - mn;
  float scale = (rge > 1e-20f) ? 255.0f / rge : 0.f;
  float mid = 0.5f * (mn + mx);
#pragma unroll
  for (int r = 0; r < 2; ++r) {
    int e = t + r * 1024;
    float v = m[r];
    int b = (int)((v - mn) * scale);
    b = b < 255 ? b : 255;
    float arg = fminf(fmaxf(v - mid, -60.f), 60.f);
    sP[e] = __expf(arg);
    sN[e] = __expf(-arg);
    sB[e] = (short)b;
    atomicAdd(&cnt[b], 1);
  }
  __syncthreads();
  // exclusive prefix of cnt -> bstart/bcur (wave 0, 4 bins/lane + wave scan)
  if (wv == 0) {
    int b4 = lane * 4;
    int c0 = cnt[b4], c1 = cnt[b4 + 1], c2 = cnt[b4 + 2], c3 = cnt[b4 + 3];
    int tot = c0 + c1 + c2 + c3;
    int inc = tot;
#pragma unroll
    for (int d = 1; d < 64; d <<= 1) {
      int y = __shfl_up(inc, d);
      if (lane >= d) inc += y;
    }
    int run = inc - tot;
    bstart[b4] = run; bcur[b4] = run; run += c0;
    bstart[b4 + 1] = run; bcur[b4 + 1] = run; run += c1;
    bstart[b4 + 2] = run; bcur[b4 + 2] = run; run += c2;
    bstart[b4 + 3] = run; bcur[b4 + 3] = run;
  }
  __syncthreads();
  // scatter into bucket order
#pragma unroll
  for (int r = 0; r < 2; ++r) {
    int e = t + r * 1024;
    int b = sB[e];
    int slot = atomicAdd(&bcur[b], 1);
    Sp[slot] = sP[e];
    Sn[slot] = sN[e];
    Smeta[slot] = (b << 16) | e;
  }
  __syncthreads();
  // per-bucket p/n sums (thread per bucket, avg 8 elems)
  if (t < 256) {
    int s0 = bstart[t], s1 = s0 + cnt[t];
    float ap = 0.f, an = 0.f;
    for (int q = s0; q < s1; ++q) { ap += Sp[q]; an += Sn[q]; }
    bsP[t] = ap; bsN[t] = an;
  }
  __syncthreads();
  // bucket-level exclusive prefix(P) and exclusive suffix(N) (wave 0)
  if (wv == 0) {
    int b4 = lane * 4;
    float p0 = bsP[b4], p1 = bsP[b4 + 1], p2 = bsP[b4 + 2], p3 = bsP[b4 + 3];
    float n0 = bsN[b4], n1 = bsN[b4 + 1], n2 = bsN[b4 + 2], n3 = bsN[b4 + 3];
    float tp = p0 + p1 + p2 + p3, tn = n0 + n1 + n2 + n3;
    float ip = tp, in_ = tn;
#pragma unroll
    for (int d = 1; d < 64; d <<= 1) {
      float yp = __shfl_up(ip, d);
      float yn = __shfl_up(in_, d);
      if (lane >= d) { ip += yp; in_ += yn; }
    }
    float totn = __shfl(in_, 63);
    float runp = ip - tp;
    float runn = in_ - tn;
    Pbel[b4] = runp; Nab[b4] = totn - runn - n0; runp += p0; runn += n0;
    Pbel[b4 + 1] = runp; Nab[b4 + 1] = totn - runn - n1; runp += p1; runn += n1;
    Pbel[b4 + 2] = runp; Nab[b4 + 2] = totn - runn - n2; runp += p2; runn += n2;
    Pbel[b4 + 3] = runp; Nab[b4 + 3] = totn - runn - n3;
  }
  __syncthreads();
  // per-slot feature = n*P_below + p*N_above + exact own-bucket pairwise
#pragma unroll
  for (int r = 0; r < 2; ++r) {
    int s = t + r * 1024;
    int meta = Smeta[s];
    int b = meta >> 16;
    int idx = meta & 0xFFFF;
    float p = Sp[s], n = Sn[s];
    float acc = n * Pbel[b] + p * Nab[b];
    int q0 = bstart[b], q1 = q0 + cnt[b];
    for (int q = q0; q < q1; ++q) acc += fminf(p * Sn[q], n * Sp[q]);
    featsT[(long)f * 2048 + idx] = acc;
  }
}

// ---------- final: out[i] = h2[i,:] . Wf[0:256] + featsT[:,i] . Wf[256:356] + bf ----------
__global__ __launch_bounds__(256) void k_final(const float* __restrict__ h2f,
                                               const float* __restrict__ featsT,
                                               const float* __restrict__ Wf,
                                               const float* __restrict__ bfp,
                                               float* __restrict__ out) {
  int wv = threadIdx.x >> 6, lane = threadIdx.x & 63;
  long i = (long)blockIdx.x * 4 + wv;
  const float* hrow = h2f + i * 256;
  float s = 0.f;
#pragma unroll
  for (int c = lane; c < 256; c += 64) s += hrow[c] * Wf[c];
  for (int f = lane; f < 100; f += 64) s += featsT[(long)f * 2048 + i] * Wf[256 + f];
#pragma unroll
  for (int off = 32; off; off >>= 1) s += __shfl_down(s, off);
  if (lane == 0) out[i] = s + bfp[0];
}

extern "C" void kernel_launch(void* const* d_in, const int* in_sizes, int n_in,
                              void* d_out, int out_size, void* d_ws, size_t ws_size,
                              hipStream_t stream) {
  const float* x  = (const float*)d_in[0];
  const float* W1 = (const float*)d_in[1];
  const float* b1 = (const float*)d_in[2];
  const float* W2 = (const float*)d_in[3];
  const float* b2 = (const float*)d_in[4];
  const float* T  = (const float*)d_in[5];
  const float* Wf = (const float*)d_in[6];
  const float* bf = (const float*)d_in[7];
  float* out = (float*)d_out;

  char* w = (char*)d_ws;
  auto alloc = [&](size_t b) { char* p = w; w += (b + 255) & ~(size_t)255; return p; };
  char*           xbr  = alloc(2048L * 3072 * 2);   // 12 MB, reused after G1
  __hip_bfloat16* xb   = (__hip_bfloat16*)xbr;
  float*          P2   = (float*)xbr;               // alias: live after xb dead
  float*          P3   = (float*)(xbr + 4194304);   // alias: 4 MB (4 z-partials, transposed)
  float*          feT  = (float*)(xbr + 8388608);   // alias
  __hip_bfloat16* W1t  = (__hip_bfloat16*)alloc(512L * 3072 * 2);
  __hip_bfloat16* W2t  = (__hip_bfloat16*)alloc(256L * 512 * 2);
  __hip_bfloat16* Tt   = (__hip_bfloat16*)alloc(128L * 256 * 2);
  __hip_bfloat16* h1b  = (__hip_bfloat16*)alloc(2048L * 512 * 2);
  float*          h2f  = (float*)alloc(2048L * 256 * 4);
  __hip_bfloat16* h2b  = (__hip_bfloat16*)alloc(2048L * 256 * 2);
  float*          P1   = (float*)alloc(3L * 2048 * 512 * 4);  // 12 MB

  // x -> bf16
  k_convert<<<6144, 256, 0, stream>>>(x, xb, 1572864);
  // weight transposes (bf16, zero-padded)
  k_transpose<<<dim3(96, 16), dim3(32, 8), 0, stream>>>(W1, W1t, 3072, 512);
  k_transpose<<<dim3(16, 8),  dim3(32, 8), 0, stream>>>(W2, W2t, 512, 256);
  k_transpose<<<dim3(8, 4),   dim3(32, 8), 0, stream>>>(T,  Tt,  256, 100);
  // h1 = leakyrelu(x @ W1 + b1): split-K=3 (768 blocks, 3/CU)
  k_gemm<false><<<dim3(32, 8, 3), 256, 0, stream>>>(xb, W1t, P1, 2048, 512, 3072, 1024, 512);
  k_comb<3, false><<<1024, 256, 0, stream>>>(P1, b1, nullptr, h1b, 262144, 511);
  // h2 = leakyrelu(h1 @ W2 + b2): split-K=2
  k_gemm<false><<<dim3(32, 4, 2), 256, 0, stream>>>(h1b, W2t, P2, 2048, 256, 512, 256, 256);
  k_comb<2, true><<<512, 256, 0, stream>>>(P2, b2, h2f, h2b, 131072, 255);
  // m = h2 @ T: split-K=4, partials stored transposed (mTz[128][2048] per z)
  k_gemm<true><<<dim3(32, 2, 4), 256, 0, stream>>>(h2b, Tt, P3, 2048, 128, 256, 64, 2048);
  // minibatch-discrimination features via value bucketing (O(B))
  k_bucketfeats<<<100, 1024, 0, stream>>>(P3, feT);
  // final dot
  k_final<<<512, 256, 0, stream>>>(h2f, feT, Wf, bf, out);
}